// Round 5
// baseline (859.781 us; speedup 1.0000x reference)
//
#include <hip/hip_runtime.h>
#include <cstdint>
#include <cstddef>

// ---------------------------------------------------------------------------
// SpikingCoreFlow: bit-exact replication of the JAX reference on MI355X.
//
// Dims: B=128, D_in=1024, n_cores=64, N=256, A=256, n_out=10, cycles=32,
// pool_width = 17410.
//
// Pool "Pb" (bytes, rows of 128 = B):
//   rows [0, 32768)        : spikes, row = t*1024 + d
//   rows [32768, 49152)    : buffer ping (A), row = 32768 + c*256 + n
//   rows [49152, 65536)    : buffer pong (B)
//   row 65536 / 65537      : zeros / ones columns
// Cycle t reads parity A if t even, writes the other.
//
// Exactness (verified R2-R4, absmax == 0.0):
//  - threefry2x32 with jax_threefry_partitionable=True semantics.
//  - einsum 'cna,bca->cbn' = single ascending-a fused-FMA chain from 0 per
//    (c,b,n); memb += E is one more rounded add. v_pk_fma_f32 = 2 independent
//    IEEE FMAs -> per-element chain unchanged -> bit-exact.
//
// R5 perf change: R3/R4 were BOTH bound by wave-uniform weight loads (lane=b
// made weights uniform -> compiler scalarizes to s_load -> ~190cy/iter K$
// serialization, 19us/dispatch). New core: lane = n (quad). Weights stream as
// per-lane coalesced global_load_dwordx4 (pipelines deeply); masks are the
// uniform operand (8B/iter via 2 broadcast ds_read_b64). Explicit 2-deep
// chunk prefetch (named ping-pong regs). pk_fma over b-pairs.
// ---------------------------------------------------------------------------

#define N_CORES   64
#define NN        256
#define AA        256
#define BB        128
#define DIN       1024
#define NOUT      10
#define CYCLES    32
#define ROW_SPK   0u
#define ROW_A     32768u
#define ROW_B     49152u
#define ROW_ZERO  65536u
#define ROW_ONE   65537u

typedef float v2f __attribute__((ext_vector_type(2)));

__device__ __forceinline__ void tf_round(uint32_t& x0, uint32_t& x1, int r) {
    x0 += x1;
    x1 = (x1 << r) | (x1 >> (32 - r));
    x1 ^= x0;
}

__device__ __forceinline__ void threefry2x32(uint32_t k0, uint32_t k1,
                                             uint32_t c0, uint32_t c1,
                                             uint32_t& o0, uint32_t& o1) {
    uint32_t ks2 = k0 ^ k1 ^ 0x1BD11BDAu;
    uint32_t x0 = c0 + k0, x1 = c1 + k1;
    tf_round(x0,x1,13); tf_round(x0,x1,15); tf_round(x0,x1,26); tf_round(x0,x1,6);
    x0 += k1; x1 += ks2 + 1u;
    tf_round(x0,x1,17); tf_round(x0,x1,29); tf_round(x0,x1,16); tf_round(x0,x1,24);
    x0 += ks2; x1 += k0 + 2u;
    tf_round(x0,x1,13); tf_round(x0,x1,15); tf_round(x0,x1,26); tf_round(x0,x1,6);
    x0 += k0; x1 += k1 + 3u;
    tf_round(x0,x1,17); tf_round(x0,x1,29); tf_round(x0,x1,16); tf_round(x0,x1,24);
    x0 += k1; x1 += ks2 + 4u;
    tf_round(x0,x1,13); tf_round(x0,x1,15); tf_round(x0,x1,26); tf_round(x0,x1,6);
    x0 += ks2; x1 += k0 + 5u;
    o0 = x0; o1 = x1;
}

__global__ void spikes_kernel(const float* __restrict__ x,
                              unsigned char* __restrict__ Pb) {
    __shared__ unsigned char S[32 * 132];
    int bx  = blockIdx.x;        // 1024 = 32 t * 32 dblk
    int t   = bx >> 5;
    int d0  = (bx & 31) * 32;
    int tid = threadIdx.x;

    uint32_t k0, k1;
    threefry2x32(0u, 42u, 0u, (uint32_t)t, k0, k1);   // keys[t] = (w0, w1)

    #pragma unroll
    for (int k = 0; k < 16; ++k) {
        int e  = tid + k * 256;      // 0..4095 = 128 bb * 32 dl
        int bb = e >> 5;
        int dl = e & 31;
        int d  = d0 + dl;
        uint32_t f = (uint32_t)(bb * 1024 + d);
        uint32_t y0, y1;
        threefry2x32(k0, k1, 0u, f, y0, y1);
        uint32_t bits = y0 ^ y1;                      // xor-fold
        float u = __uint_as_float((bits >> 9) | 0x3f800000u) - 1.0f;
        S[dl * 132 + bb] = (u < x[bb * 1024 + d]) ? 1 : 0;
    }
    __syncthreads();

    int dl = tid >> 3;
    int bg = tid & 7;
    const uint32_t* Srow = (const uint32_t*)(S + dl * 132);
    uint4 v;
    v.x = Srow[bg * 4 + 0]; v.y = Srow[bg * 4 + 1];
    v.z = Srow[bg * 4 + 2]; v.w = Srow[bg * 4 + 3];
    size_t row = (size_t)t * 1024 + d0 + dl;
    *(uint4*)(Pb + row * 128 + bg * 16) = v;
}

// WT[c][a][n] = W[c][n][a]
__global__ void wt_kernel(const float* __restrict__ W, float* __restrict__ WT) {
    __shared__ float T[32][33];
    int bx = blockIdx.x;            // 4096 = 64 c * 8 tn * 8 ta
    int c  = bx >> 6;
    int tn = (bx >> 3) & 7;
    int ta = bx & 7;
    int tid = threadIdx.x;
    int r  = tid >> 3;
    int q4 = (tid & 7) * 4;

    const float* src = W + (size_t)c * 65536 + (size_t)(tn * 32 + r) * 256 + ta * 32 + q4;
    float4 v = *(const float4*)src;
    T[r][q4 + 0] = v.x; T[r][q4 + 1] = v.y; T[r][q4 + 2] = v.z; T[r][q4 + 3] = v.w;
    __syncthreads();

    float4 o;
    o.x = T[q4 + 0][r]; o.y = T[q4 + 1][r]; o.z = T[q4 + 2][r]; o.w = T[q4 + 3][r];
    float* dst = WT + (size_t)c * 65536 + (size_t)(ta * 32 + r) * 256 + tn * 32 + q4;
    *(float4*)dst = o;
}

__global__ void offtab_kernel(const int* __restrict__ axon,
                              const int* __restrict__ outsrc,
                              uint32_t* __restrict__ off_tab,
                              uint32_t* __restrict__ out_off) {
    int bx = blockIdx.x;
    int tid = threadIdx.x;
    if (bx < 2048) {
        int idx = bx * 256 + tid;          // [t][c*256+a]
        int t   = idx >> 14;
        int ca  = idx & 16383;
        int j   = axon[ca];
        uint32_t row;
        if (j < 1024)        row = (uint32_t)(t * 1024 + j);
        else if (j < 17408)  row = (((t & 1) == 0) ? ROW_A : ROW_B) + (uint32_t)(j - 1024);
        else                 row = (j == 17408) ? ROW_ZERO : ROW_ONE;
        off_tab[idx] = row * 128u;
    } else {
        for (int idx = tid; idx < CYCLES * NOUT; idx += 256) {
            int t = idx / NOUT, o = idx % NOUT;
            int j = outsrc[o];
            uint32_t row;
            if (j < 1024)        row = (uint32_t)(t * 1024 + j);
            else if (j < 17408)  row = (((t & 1) == 0) ? ROW_B : ROW_A) + (uint32_t)(j - 1024);
            else                 row = (j == 17408) ? ROW_ZERO : ROW_ONE;
            out_off[idx] = row * 128u;
        }
    }
}

// One cycle. 512 blocks x 256 thr = (c, b-group of 16) via XCD swizzle.
// Phase 1: gather 256a x 16b mask bytes -> LDS floats, row stride 18 dwords.
// Phase 2: 4 waves = 4 b-quads. lane = n-quad. Per a: 1 coalesced
// global_load_dwordx4 (weights, per-lane) + 2 uniform ds_read_b64 (4 masks)
// + 8 v_pk_fma_f32. Chunked (8 a) double-buffered prefetch, named regs.
#define MF_ST 18   // Mf row stride in dwords (72B: b64-aligned, 4-way-max bank)

__global__ __launch_bounds__(256, 2) void core_kernel(
    const unsigned char* __restrict__ Pb,
    unsigned char* __restrict__ Pw,
    const float* __restrict__ WT,
    const uint32_t* __restrict__ off_t,
    float* __restrict__ memb,
    const float* __restrict__ thresholds,
    uint32_t wbyte_base,
    const uint32_t* __restrict__ out_off_prev,
    float* __restrict__ d_out,
    int do_out)
{
    __shared__ float Mf[256 * MF_ST];   // 18 KB

    int tid = threadIdx.x;
    int bx  = blockIdx.x;

    // fused out-update for the PREVIOUS cycle (reads buf written last kernel)
    if (do_out && bx == 511 && tid < BB) {
        #pragma unroll
        for (int o = 0; o < NOUT; ++o) {
            uint32_t off = out_off_prev[o];
            d_out[tid * NOUT + o] += (float)Pb[off + (uint32_t)tid];
        }
    }

    // decode: 512 = 8 xcd * 8 c-local * 8 b-group (c grouped per XCD for L2)
    int c     = (bx & 7) * 8 + ((bx >> 3) & 7);
    int bg    = bx >> 6;             // 0..7
    int b0blk = bg * 16;

    // ---- Phase 1: gather masks -> LDS floats (thread = a) ----
    {
        uint32_t off = off_t[c * 256 + tid];            // coalesced
        uint4 v = *(const uint4*)(Pb + off + (uint32_t)b0blk);
        const unsigned char* pb = (const unsigned char*)&v;
        float* dst = Mf + tid * MF_ST;
        #pragma unroll
        for (int j = 0; j < 8; ++j) {
            float2 p;
            p.x = (float)pb[2 * j];
            p.y = (float)pb[2 * j + 1];
            *(float2*)(dst + 2 * j) = p;                // b64 writes, 4-way max
        }
    }
    __syncthreads();

    int lane = tid & 63;
    int wid  = __builtin_amdgcn_readfirstlane(tid >> 6);
    int wb0  = wid * 4;              // wave's b-offset within the 16
    int b0   = b0blk + wb0;          // global b base (4 b's per wave)

    const float* wt   = WT + (size_t)c * 65536 + lane * 4;  // + a*256 per iter
    const float* mrow = Mf + wb0;                            // + a*MF_ST per iter

    v2f acc[4][2];                   // [nj][bp], pk over b-pair
    #pragma unroll
    for (int nj = 0; nj < 4; ++nj)
        #pragma unroll
        for (int bp = 0; bp < 2; ++bp) acc[nj][bp] = (v2f){0.0f, 0.0f};

    // ---- Phase 2: chunked (8 a) double-buffered, exact ascending-a chain ----
    float4 wA[8], wB[8];
    v2f    mA[8][2], mB[8][2];

#define LOADCH(Wb, Mb, ch)                                                    \
    { int a0 = (ch) * 8;                                                      \
      _Pragma("unroll")                                                       \
      for (int j = 0; j < 8; ++j) {                                           \
          Wb[j] = *(const float4*)(wt + (size_t)(a0 + j) * 256);              \
          Mb[j][0] = *(const v2f*)(mrow + (a0 + j) * MF_ST);                  \
          Mb[j][1] = *(const v2f*)(mrow + (a0 + j) * MF_ST + 2);              \
      } }

#define FMACH(Wb, Mb)                                                         \
    { _Pragma("unroll")                                                       \
      for (int j = 0; j < 8; ++j) {                                           \
          float4 w = Wb[j];                                                   \
          v2f w2;                                                             \
          w2 = (v2f){w.x, w.x};                                               \
          acc[0][0] = __builtin_elementwise_fma(w2, Mb[j][0], acc[0][0]);     \
          acc[0][1] = __builtin_elementwise_fma(w2, Mb[j][1], acc[0][1]);     \
          w2 = (v2f){w.y, w.y};                                               \
          acc[1][0] = __builtin_elementwise_fma(w2, Mb[j][0], acc[1][0]);     \
          acc[1][1] = __builtin_elementwise_fma(w2, Mb[j][1], acc[1][1]);     \
          w2 = (v2f){w.z, w.z};                                               \
          acc[2][0] = __builtin_elementwise_fma(w2, Mb[j][0], acc[2][0]);     \
          acc[2][1] = __builtin_elementwise_fma(w2, Mb[j][1], acc[2][1]);     \
          w2 = (v2f){w.w, w.w};                                               \
          acc[3][0] = __builtin_elementwise_fma(w2, Mb[j][0], acc[3][0]);     \
          acc[3][1] = __builtin_elementwise_fma(w2, Mb[j][1], acc[3][1]);     \
      } }

    LOADCH(wA, mA, 0);
    #pragma unroll
    for (int ch = 0; ch < 32; ch += 2) {
        if (ch + 1 < 32) LOADCH(wB, mB, ch + 1);
        FMACH(wA, mA);
        if (ch + 2 < 32) LOADCH(wA, mA, ch + 2);
        FMACH(wB, mB);
    }
#undef LOADCH
#undef FMACH

    // ---- Epilogue: scattered RMW (lane-stride 2KB; 8B/2B units) ----
    float thr = thresholds[c];
    #pragma unroll
    for (int nj = 0; nj < 4; ++nj) {
        int n = 4 * lane + nj;
        size_t rowb = (size_t)(c * 256 + n) * 128;
        #pragma unroll
        for (int bp = 0; bp < 2; ++bp) {
            size_t idx = rowb + (size_t)(b0 + 2 * bp);
            float2 mv = *(float2*)(memb + idx);
            float v0_ = mv.x + acc[nj][bp].x;           // single rounded add
            float v1_ = mv.y + acc[nj][bp].y;
            bool f0 = v0_ > thr;
            bool f1 = v1_ > thr;
            float2 st;
            st.x = f0 ? 0.0f : v0_;
            st.y = f1 ? 0.0f : v1_;
            *(float2*)(memb + idx) = st;
            unsigned short fb = (unsigned short)((f0 ? 1u : 0u) | ((f1 ? 1u : 0u) << 8));
            *(unsigned short*)(Pw + wbyte_base + idx) = fb;
        }
    }
}

__global__ void tail_kernel(const unsigned char* __restrict__ Pb,
                            const uint32_t* __restrict__ out_off31,
                            float* __restrict__ d_out) {
    int tid = threadIdx.x;
    if (tid < BB) {
        #pragma unroll
        for (int o = 0; o < NOUT; ++o) {
            uint32_t off = out_off31[o];
            d_out[tid * NOUT + o] += (float)Pb[off + (uint32_t)tid];
        }
    }
}

extern "C" void kernel_launch(void* const* d_in, const int* in_sizes, int n_in,
                              void* d_out_, int out_size, void* d_ws, size_t ws_size,
                              hipStream_t stream) {
    const float* x          = (const float*)d_in[0];
    const float* W          = (const float*)d_in[1];
    const float* thresholds = (const float*)d_in[2];
    const int*   axon       = (const int*)d_in[3];
    const int*   outsrc     = (const int*)d_in[4];
    // d_in[5] = cycles; fixed instance -> 32.

    if (ws_size < (size_t)45 * 1024 * 1024) return;

    unsigned char* ws      = (unsigned char*)d_ws;
    unsigned char* Pb      = ws;                                    // 8.4 MB
    float*         WT      = (float*)(ws + (size_t)(16u << 20));    // 16 MiB
    uint32_t*      off_tab = (uint32_t*)(ws + (size_t)(32u << 20)); // 2 MiB
    uint32_t*      out_off = (uint32_t*)(ws + (size_t)(32u << 20) + 2u * 1024u * 1024u);
    float*         memb    = (float*)(ws + (size_t)(36u << 20));    // 8 MiB
    float*         out     = (float*)d_out_;

    hipMemsetAsync(memb, 0, (size_t)N_CORES * NN * BB * sizeof(float), stream);
    hipMemsetAsync(Pb + (size_t)ROW_A * 128, 0, (size_t)16384 * 128, stream);
    hipMemsetAsync(Pb + (size_t)ROW_ZERO * 128, 0, 128, stream);
    hipMemsetAsync(Pb + (size_t)ROW_ONE * 128, 1, 128, stream);
    hipMemsetAsync(out, 0, (size_t)BB * NOUT * sizeof(float), stream);

    spikes_kernel<<<1024, 256, 0, stream>>>(x, Pb);
    wt_kernel<<<4096, 256, 0, stream>>>(W, WT);
    offtab_kernel<<<2049, 256, 0, stream>>>(axon, outsrc, off_tab, out_off);

    for (int t = 0; t < CYCLES; ++t) {
        uint32_t wrow = ((t & 1) == 0) ? ROW_B : ROW_A;   // write parity
        const uint32_t* oprev = out_off + (t > 0 ? (t - 1) * NOUT : 0);
        core_kernel<<<512, 256, 0, stream>>>(
            Pb, Pb, WT, off_tab + (size_t)t * 16384, memb, thresholds,
            wrow * 128u, oprev, out, t > 0 ? 1 : 0);
    }
    tail_kernel<<<1, 128, 0, stream>>>(Pb, out_off + 31 * NOUT, out);
}